// Round 6
// baseline (47.959 us; speedup 1.0000x reference)
//
#include <hip/hip_runtime.h>

typedef _Float16 h2 __attribute__((ext_vector_type(2)));
typedef _Float16 h8 __attribute__((ext_vector_type(8)));
typedef float f4 __attribute__((ext_vector_type(4)));
typedef unsigned int uint32;

#define NVAL 20
#define CDIM 64
#define HW   65536
#define NPIX (4*HW)

#define BLK   512
#define NWAVE (BLK/64)
#define MAXSUB  52                // sum ceil(n_k/16) <= 512/16 + 19 = 51
#define MAXSLOT (MAXSUB*16)       // 832

// ---- packed f16 tables in ws (bytes) ----
// KN: per class 20 j-rows x 128 B (64 f16, c-contiguous)
#define KN_OFF      0
#define KN_KSTRIDE  2560
// VAL: per class 64 c-rows x 64 B (32 j-slots: j0..19 real, j20=rest, j21..31=0)
#define VAL_OFF     (20*KN_KSTRIDE)      // 51200
#define VAL_KSTRIDE 4096
#define VAL_CSTRIDE 64

// ---- LDS layout (bytes) ----
#define ROW_STRIDE 144            // 64 f16 (128 B) + 16 pad; 16B-aligned rows
#define ROWS_BYTES (BLK*ROW_STRIDE)          // 73728
#define INV_OFF   ROWS_BYTES                 // BLK f32           (2048)
#define PERM_OFF  (INV_OFF + BLK*4)          // MAXSLOT ushort    (1664)
#define SCLS_OFF  (PERM_OFF + MAXSLOT*2)     // MAXSUB int        (208)
#define CNT_OFF   (SCLS_OFF + MAXSUB*4)      // 24 int
#define BASE_OFF  (CNT_OFF + 24*4)           // 24 int
#define NT_OFF    (BASE_OFF + 24*4)
#define LDS_TOTAL (NT_OFF + 16)              // ~77.9 KB -> 2 blocks/CU

static __device__ __forceinline__ h2 bch2(uint32 u) { return __builtin_bit_cast(h2, u); }
static __device__ __forceinline__ uint32 bcu(h2 v) { return __builtin_bit_cast(uint32, v); }
static __device__ __forceinline__ h8 bch8(uint4 u) { return __builtin_bit_cast(h8, u); }
static __device__ __forceinline__ h2 pkrtz(float a, float b) {
    return __builtin_bit_cast(h2, __builtin_amdgcn_cvt_pkrtz(a, b));
}

// ---------------------------------------------------------------------------
// Prep: build packed f16 tables in ws.
// ---------------------------------------------------------------------------
__global__ void prep_kernel(const float* __restrict__ key,
                            const float* __restrict__ val,
                            unsigned char* __restrict__ ws) {
    int i = blockIdx.x * 256 + threadIdx.x;
    if (i < 20*CDIM) {
        int k = i >> 6, c = i & 63;
        const float* vb = val + k*NVAL*CDIM + c;     // val[k][j][c]
        float v[NVAL];
        float s = 0.f;
        #pragma unroll
        for (int j = 0; j < NVAL; j++) { v[j] = vb[j*CDIM]; s += v[j]; }
        float t = 0.f;
        for (int kk = 0; kk < 20; kk++) {
            const float* vb2 = val + kk*NVAL*CDIM + c;
            #pragma unroll
            for (int j = 0; j < NVAL; j++) t += vb2[j*CDIM];
        }
        float rest = (t - s) * (1.0f/NVAL);
        uint32* row = (uint32*)(ws + VAL_OFF + (size_t)k*VAL_KSTRIDE + c*VAL_CSTRIDE);
        #pragma unroll
        for (int jp = 0; jp < 10; jp++) row[jp] = bcu(pkrtz(v[2*jp], v[2*jp+1]));
        row[10] = bcu(pkrtz(rest, 0.f));
        #pragma unroll
        for (int jp = 11; jp < 16; jp++) row[jp] = 0u;
    } else if (i < 20*CDIM + 20*NVAL) {
        int idx = i - 20*CDIM;
        int k = idx / NVAL, j = idx % NVAL;
        const float* kb = key + k*CDIM*NVAL + j;     // key[k][c][j]
        float x[CDIM];
        float ssq = 0.f;
        #pragma unroll
        for (int c = 0; c < CDIM; c++) { x[c] = kb[c*NVAL]; ssq = fmaf(x[c], x[c], ssq); }
        float inv = 1.0f / fmaxf(sqrtf(ssq), 1e-12f);
        uint32* row = (uint32*)(ws + KN_OFF + (size_t)k*KN_KSTRIDE + j*128);
        #pragma unroll
        for (int cp = 0; cp < 32; cp++) row[cp] = bcu(pkrtz(x[2*cp]*inv, x[2*cp+1]*inv));
    }
}

// ---------------------------------------------------------------------------
// Main: 512 blocks x 512 threads. Counting-sort pixels into class-pure
// 16-pixel SUBTILES (1.2x padding vs 2.5x at 64). A wave-iteration processes
// 4 subtiles (n=0..3), each with its own class -> per-n A-fragments from the
// global f16 tables; X/W/O live in per-pixel LDS rows.
// ---------------------------------------------------------------------------
__global__ __launch_bounds__(BLK, 4) void main_kernel(
        const float* __restrict__ content, const int* __restrict__ seg,
        const unsigned char* __restrict__ tabs, float* __restrict__ out) {
    extern __shared__ unsigned char lds[];
    float* invA = (float*)(lds + INV_OFF);
    unsigned short* perm = (unsigned short*)(lds + PERM_OFF);
    int* scls = (int*)(lds + SCLS_OFF);
    int* cnt  = (int*)(lds + CNT_OFF);
    int* base = (int*)(lds + BASE_OFF);
    int* ntp  = (int*)(lds + NT_OFF);

    const int tid  = threadIdx.x;
    const int gp0  = blockIdx.x * BLK;
    const int b    = gp0 >> 16;
    const int pim0 = gp0 & (HW - 1);

    if (tid < 24) cnt[tid] = 0;
    if (tid < MAXSUB) scls[tid] = 0;
    for (int i = tid; i < MAXSLOT; i += BLK) perm[i] = 0xFFFFu;
    __syncthreads();

    const int cls = seg[gp0 + tid] + 1;          // 1..19
    const int myrank = atomicAdd(&cnt[cls], 1);

    // stage content -> own LDS row (f16, c-contiguous) + inv; coalesced reads
    {
        const float* cptr = content + (size_t)b * CDIM * HW + pim0 + tid;
        uint2* myrow = (uint2*)(lds + tid * ROW_STRIDE);
        float ssq = 0.f;
        #pragma unroll
        for (int q = 0; q < 16; q++) {
            float f0 = cptr[(size_t)(4*q+0) * HW];
            float f1 = cptr[(size_t)(4*q+1) * HW];
            float f2 = cptr[(size_t)(4*q+2) * HW];
            float f3 = cptr[(size_t)(4*q+3) * HW];
            ssq = fmaf(f0,f0,ssq); ssq = fmaf(f1,f1,ssq);
            ssq = fmaf(f2,f2,ssq); ssq = fmaf(f3,f3,ssq);
            uint2 o; o.x = bcu(pkrtz(f0,f1)); o.y = bcu(pkrtz(f2,f3));
            myrow[q] = o;
        }
        invA[tid] = 1.0f / fmaxf(sqrtf(ssq), 1e-12f);
    }
    __syncthreads();

    if (tid == 0) {
        int off = 0;
        for (int k = 1; k <= 20; k++) { base[k] = off; off += (cnt[k] + 15) & ~15; }
        *ntp = off >> 4;                          // number of 16-px subtiles
    }
    __syncthreads();
    {
        int slot = base[cls] + myrank;
        perm[slot] = (unsigned short)tid;
        scls[slot >> 4] = cls;                   // subtile is class-pure
    }
    __syncthreads();

    const int nsub = *ntp;
    const int ntw  = (nsub + 3) >> 2;            // wave-iterations (4 subtiles each)
    const int wave = tid >> 6, lane = tid & 63;
    const int g = lane >> 4, r16 = lane & 15;

    for (int it = wave; it < ntw; it += NWAVE) {
        int uu[4], rowb[4];
        float invn[4];
        bool mine[4];
        #pragma unroll
        for (int n = 0; n < 4; n++) {
            int sN = it*4 + n;                   // <= 51 < MAXSUB always
            uu[n] = __builtin_amdgcn_readfirstlane(scls[sN]);
            int v = perm[sN*16 + r16];
            mine[n] = (v != 0xFFFF);
            int l = mine[n] ? v : 0;
            rowb[n] = l * ROW_STRIDE;
            invn[n] = invA[l];
        }

        // ---- scores S^T[j][p] = sum_c Kn^T[j][c] * X^T[c][p], per-n class ----
        f4 sacc[2][4];
        #pragma unroll
        for (int m = 0; m < 2; m++)
            #pragma unroll
            for (int n = 0; n < 4; n++) sacc[m][n] = (f4){0.f,0.f,0.f,0.f};
        #pragma unroll
        for (int n = 0; n < 4; n++) {
            const unsigned char* knc = tabs + KN_OFF + (size_t)uu[n] * KN_KSTRIDE;
            uint4 b0 = *(const uint4*)(lds + rowb[n] + (g*8)*2);
            uint4 b1 = *(const uint4*)(lds + rowb[n] + (32 + g*8)*2);
            #pragma unroll
            for (int m = 0; m < 2; m++) {
                uint4 a0 = *(const uint4*)(knc + (m*16 + r16)*128 + (g*8)*2);
                uint4 a1 = *(const uint4*)(knc + (m*16 + r16)*128 + (32 + g*8)*2);
                sacc[m][n] = __builtin_amdgcn_mfma_f32_16x16x32_f16(
                    bch8(a0), bch8(b0), sacc[m][n], 0, 0, 0);
                sacc[m][n] = __builtin_amdgcn_mfma_f32_16x16x32_f16(
                    bch8(a1), bch8(b1), sacc[m][n], 0, 0, 0);
            }
        }

        // ---- softmax; lane holds j = m*16 + g*4 + r for pixel p = n-subtile,r16 ----
        uint2 w0[4], w1[4];
        #pragma unroll
        for (int n = 0; n < 4; n++) {
            float e0[4], e1[4];
            #pragma unroll
            for (int r = 0; r < 4; r++) e0[r] = __expf(sacc[0][n][r] * invn[n]);
            float arg1 = (g == 0) ? invn[n] : 0.0f;     // j>=20 masked
            #pragma unroll
            for (int r = 0; r < 4; r++) e1[r] = __expf(sacc[1][n][r] * arg1);
            float s = e0[0]+e0[1]+e0[2]+e0[3];
            s += (g == 0) ? (e1[0]+e1[1]+e1[2]+e1[3]) : 0.0f;
            s += __shfl_xor(s, 16, 64);
            s += __shfl_xor(s, 32, 64);
            float wsc = 1.0f / s;
            w0[n].x = bcu(pkrtz(e0[0]*wsc, e0[1]*wsc));
            w0[n].y = bcu(pkrtz(e0[2]*wsc, e0[3]*wsc));
            uint2 t1;
            if (g == 0)      { t1.x = bcu(pkrtz(e1[0]*wsc, e1[1]*wsc));
                               t1.y = bcu(pkrtz(e1[2]*wsc, e1[3]*wsc)); }
            else if (g == 1) { t1.x = 0x00003C00u; t1.y = 0u; }  // j20=1.0 (rest)
            else             { t1.x = 0u; t1.y = 0u; }
            w1[n] = t1;
        }
        // write W over own row (X is dead): j-contiguous 32 f16 at offset 0
        #pragma unroll
        for (int n = 0; n < 4; n++) {
            if (mine[n]) {
                *(uint2*)(lds + rowb[n] + g*8)      = w0[n];
                *(uint2*)(lds + rowb[n] + 32 + g*8) = w1[n];
            }
        }

        // ---- PV O^T[c][p] = sum_j V^T[c][j] * W^T[j][p] (K=32), per-n class ----
        uint4 b_pv[4];
        #pragma unroll
        for (int n = 0; n < 4; n++)
            b_pv[n] = *(const uint4*)(lds + rowb[n] + g*16);
        #pragma unroll
        for (int n = 0; n < 4; n++) {
            const unsigned char* vc = tabs + VAL_OFF + (size_t)uu[n] * VAL_KSTRIDE;
            #pragma unroll
            for (int m = 0; m < 4; m++) {
                uint4 a = *(const uint4*)(vc + (m*16 + r16)*VAL_CSTRIDE + g*16);
                f4 o = (f4){0.f,0.f,0.f,0.f};
                o = __builtin_amdgcn_mfma_f32_16x16x32_f16(bch8(a), bch8(b_pv[n]), o, 0, 0, 0);
                uint2 ov; ov.x = bcu(pkrtz(o[0], o[1])); ov.y = bcu(pkrtz(o[2], o[3]));
                if (mine[n])
                    *(uint2*)(lds + rowb[n] + m*32 + g*8) = ov;  // c = m*16+g*4..+3
            }
        }
    }
    __syncthreads();

    // coalesced f32 store from own row
    {
        const uint2* r2 = (const uint2*)(lds + tid * ROW_STRIDE);
        float* obase = out + (size_t)b * CDIM * HW + pim0 + tid;
        #pragma unroll
        for (int q = 0; q < 16; q++) {
            uint2 v = r2[q];
            h2 x = bch2(v.x), y = bch2(v.y);
            obase[(size_t)(4*q+0) * HW] = (float)x[0];
            obase[(size_t)(4*q+1) * HW] = (float)x[1];
            obase[(size_t)(4*q+2) * HW] = (float)y[0];
            obase[(size_t)(4*q+3) * HW] = (float)y[1];
        }
    }
}

extern "C" void kernel_launch(void* const* d_in, const int* in_sizes, int n_in,
                              void* d_out, int out_size, void* d_ws, size_t ws_size,
                              hipStream_t stream) {
    const float* content = (const float*)d_in[0];
    const int*   seg     = (const int*)d_in[1];
    const float* key     = (const float*)d_in[2];
    const float* val     = (const float*)d_in[3];
    float* out = (float*)d_out;
    unsigned char* ws = (unsigned char*)d_ws;

    prep_kernel<<<7, 256, 0, stream>>>(key, val, ws);

    (void)hipFuncSetAttribute((const void*)main_kernel,
                              hipFuncAttributeMaxDynamicSharedMemorySize, LDS_TOTAL);
    main_kernel<<<NPIX/BLK, BLK, LDS_TOTAL, stream>>>(content, seg, ws, out);
}